// Round 11
// baseline (199.140 us; speedup 1.0000x reference)
//
#include <hip/hip_runtime.h>
#include <math.h>

#define B_   2
#define L_   2048
#define EMB_ 1024
#define H_   16
#define HD_  64
#define M_   (B_ * L_)   // 4096 tokens
#define LOG2E 1.44269504088896f

typedef __bf16 bf16x8 __attribute__((ext_vector_type(8)));
typedef __bf16 bf16x4 __attribute__((ext_vector_type(4)));
typedef __bf16 bf16x2 __attribute__((ext_vector_type(2)));
typedef float floatx16 __attribute__((ext_vector_type(16)));
typedef unsigned int uintx2 __attribute__((ext_vector_type(2)));

typedef __attribute__((address_space(1))) const void GV;
typedef __attribute__((address_space(3))) void LV;

#define MFMA32(a, b, c) __builtin_amdgcn_mfma_f32_32x32x16_bf16((a), (b), (c), 0, 0, 0)

#if __has_builtin(__builtin_amdgcn_exp2f)
#define EXP2(x) __builtin_amdgcn_exp2f(x)
#else
#define EXP2(x) exp2f(x)
#endif

// LDS chunk swizzle: lanes lq, lq+8, lq+16, lq+24 (same (row&7)) get distinct
// chunk slots via the (row>>3)&3 term.
#define SWZ(row) ((((row) & 7) ^ (((row) >> 3) & 3)))

// pack two floats into a bf16 pair (b32)
__device__ __forceinline__ int pkbf(float a, float b) {
#if __has_builtin(__builtin_amdgcn_cvt_pk_bf16_f32)
    union { bf16x2 v; int i; } u;
    u.v = __builtin_amdgcn_cvt_pk_bf16_f32(a, b);
    return u.i;
#else
    union { __bf16 h[2]; int i; } u;
    u.h[0] = (__bf16)a; u.h[1] = (__bf16)b;
    return u.i;
#endif
}

// ---------------------------------------------------------------------------
// Fused prep: blocks [0, M_) do LayerNorm -> bf16 (one block per token row);
// blocks [M_, M_+1024) convert the 4 weight slabs fp32 -> bf16.
// ---------------------------------------------------------------------------
__global__ __launch_bounds__(256) void prep_kernel(
        const float* __restrict__ x, const float* __restrict__ gamma,
        const float* __restrict__ beta, __bf16* __restrict__ h,
        const float* __restrict__ s0, const float* __restrict__ s1,
        const float* __restrict__ s2, const float* __restrict__ s3,
        __bf16* __restrict__ d0, __bf16* __restrict__ d1,
        __bf16* __restrict__ d2, __bf16* __restrict__ d3) {
    int bid = blockIdx.x;
    int tid = threadIdx.x;
    if (bid >= M_) {
        int wb = bid - M_;                 // 0..1023
        int z = wb >> 8;                   // slab
        const float* s = (z == 0) ? s0 : (z == 1) ? s1 : (z == 2) ? s2 : s3;
        __bf16* d = (z == 0) ? d0 : (z == 1) ? d1 : (z == 2) ? d2 : d3;
        size_t base = (size_t)((wb & 255) * 256 + tid) * 16;
#pragma unroll
        for (int j = 0; j < 4; ++j) {
            float4 f = *(const float4*)(s + base + j * 4);
            bf16x4 t;
            t[0] = (__bf16)f.x; t[1] = (__bf16)f.y; t[2] = (__bf16)f.z; t[3] = (__bf16)f.w;
            *(bf16x4*)(d + base + j * 4) = t;
        }
        return;
    }
    int row = bid;
    const float* xr = x + (size_t)row * EMB_;
    float4 v = *(const float4*)(xr + tid * 4);
    float s  = v.x + v.y + v.z + v.w;
    float ss = v.x * v.x + v.y * v.y + v.z * v.z + v.w * v.w;
    for (int off = 32; off; off >>= 1) {
        s  += __shfl_down(s, off, 64);
        ss += __shfl_down(ss, off, 64);
    }
    __shared__ float s1_[4], s2_[4];
    int wid = tid >> 6;
    if ((tid & 63) == 0) { s1_[wid] = s; s2_[wid] = ss; }
    __syncthreads();
    if (tid == 0) {
        float a = s1_[0] + s1_[1] + s1_[2] + s1_[3];
        float b = s2_[0] + s2_[1] + s2_[2] + s2_[3];
        float mu = a / EMB_;
        float var = b / EMB_ - mu * mu;
        s1_[0] = mu;
        s2_[0] = rsqrtf(var + 1e-5f);
    }
    __syncthreads();
    float mu = s1_[0], rstd = s2_[0];
    float4 g4 = *(const float4*)(gamma + tid * 4);
    float4 b4 = *(const float4*)(beta + tid * 4);
    bf16x4 o;
    o[0] = (__bf16)((v.x - mu) * rstd * g4.x + b4.x);
    o[1] = (__bf16)((v.y - mu) * rstd * g4.y + b4.y);
    o[2] = (__bf16)((v.z - mu) * rstd * g4.z + b4.z);
    o[3] = (__bf16)((v.w - mu) * rstd * g4.w + b4.w);
    *(bf16x4*)(h + (size_t)row * EMB_ + tid * 4) = o;
}

// ---------------------------------------------------------------------------
// GEMM staging: 128 rows x 64 cols bf16 tile, SWZ-swizzled 16B chunks.
// ---------------------------------------------------------------------------
__device__ __forceinline__ void stage_tile128(const __bf16* gbase, __bf16* lds,
                                              int wave, int lane) {
    int srow = lane >> 3;
    int gch0 = lane & 7;
#pragma unroll
    for (int s = 0; s < 4; ++s) {
        int seg = wave * 4 + s;
        int row = seg * 8 + srow;
        int g = gch0 ^ SWZ(row);
        __builtin_amdgcn_global_load_lds(
            (GV*)(gbase + (size_t)row * EMB_ + g * 8),
            (LV*)(lds + seg * 512 + lane * 8), 16, 0, 0);
    }
}

// ---------------------------------------------------------------------------
// Fused QKV projection GEMM: C = h @ Wqkv^T + bias, 128x128 tile, BK=64.
// Wqkv = [3072][1024] (Wq; Wk; Wv). Column block z = col>>10 selects output:
// z=0 -> Q (scaled by 0.125*log2e), z=1 -> K, z=2 -> V^T ([b][h][d][l]).
// XCD-chunked blockIdx swizzle (T1): grid 768, 96 tiles per XCD.
// ---------------------------------------------------------------------------
__global__ __launch_bounds__(256) void gemm_qkv_mfma(
        const __bf16* __restrict__ A, const __bf16* __restrict__ W,
        const float* __restrict__ bq, const float* __restrict__ bk,
        const float* __restrict__ bv,
        __bf16* __restrict__ Qo, __bf16* __restrict__ Ko,
        __bf16* __restrict__ Vto) {
    __shared__ __bf16 As[128 * 64];
    __shared__ __bf16 Bs[128 * 64];
    int tid = threadIdx.x, wave = tid >> 6, lane = tid & 63;
    int wm = wave >> 1, wn = wave & 1;
    int quad = lane >> 5, lq = lane & 31;
    // XCD-chunked swizzle: nwg=768, 96 per XCD
    int flat = blockIdx.y * gridDim.x + blockIdx.x;
    int nf = (flat & 7) * 96 + (flat >> 3);
    int bm = (nf / 24) * 128, bn = (nf % 24) * 128;

    floatx16 acc[2][2];
#pragma unroll
    for (int i = 0; i < 2; ++i)
#pragma unroll
        for (int j = 0; j < 2; ++j)
#pragma unroll
            for (int r = 0; r < 16; ++r) acc[i][j][r] = 0.f;

    for (int k0 = 0; k0 < EMB_; k0 += 64) {
        __syncthreads();
        stage_tile128(A + (size_t)bm * EMB_ + k0, As, wave, lane);
        stage_tile128(W + (size_t)bn * EMB_ + k0, Bs, wave, lane);
        __syncthreads();
#pragma unroll
        for (int s = 0; s < 4; ++s) {
            int g = 2 * s + quad;
            int r0 = wm * 64 + lq, r1 = r0 + 32;
            int c0 = wn * 64 + lq, c1 = c0 + 32;
            bf16x8 a0 = *(const bf16x8*)&As[r0 * 64 + ((g ^ SWZ(r0)) * 8)];
            bf16x8 a1 = *(const bf16x8*)&As[r1 * 64 + ((g ^ SWZ(r1)) * 8)];
            bf16x8 b0 = *(const bf16x8*)&Bs[c0 * 64 + ((g ^ SWZ(c0)) * 8)];
            bf16x8 b1 = *(const bf16x8*)&Bs[c1 * 64 + ((g ^ SWZ(c1)) * 8)];
            acc[0][0] = MFMA32(a0, b0, acc[0][0]);
            acc[0][1] = MFMA32(a0, b1, acc[0][1]);
            acc[1][0] = MFMA32(a1, b0, acc[1][0]);
            acc[1][1] = MFMA32(a1, b1, acc[1][1]);
        }
    }

#pragma unroll
    for (int mb = 0; mb < 2; ++mb) {
#pragma unroll
        for (int nb = 0; nb < 2; ++nb) {
            int col = bn + wn * 64 + nb * 32 + lq;
            int z = col >> 10;
            int cc = col & 1023;
            float bv_ = (z == 0) ? bq[cc] : (z == 1) ? bk[cc] : bv[cc];
            if (z < 2) {
                __bf16* dst = (z == 0) ? Qo : Ko;
                float qs = (z == 0) ? 0.125f * LOG2E : 1.0f;
#pragma unroll
                for (int r = 0; r < 16; ++r) {
                    int row = bm + wm * 64 + mb * 32 + (r & 3) + 8 * (r >> 2) + 4 * quad;
                    dst[(size_t)row * EMB_ + cc] = (__bf16)((acc[mb][nb][r] + bv_) * qs);
                }
            } else {
                int hh = cc >> 6, d = cc & 63;
#pragma unroll
                for (int rb = 0; rb < 4; ++rb) {
                    int row = bm + wm * 64 + mb * 32 + 8 * rb + 4 * quad;
                    int b = row >> 11, l = row & (L_ - 1);
                    bf16x4 t;
#pragma unroll
                    for (int a = 0; a < 4; ++a) t[a] = (__bf16)(acc[mb][nb][4 * rb + a] + bv_);
                    *(bf16x4*)(Vto + ((size_t)(b * H_ + hh) * HD_ + d) * L_ + l) = t;
                }
            }
        }
    }
}

// ---------------------------------------------------------------------------
// Output projection GEMM: out = O @ Wo^T + bo + x (fp32 out). 128x128 tile.
// XCD-chunked swizzle (grid 256, 32 per XCD).
// ---------------------------------------------------------------------------
__global__ __launch_bounds__(256) void gemm_out_mfma(
        const __bf16* __restrict__ A, const __bf16* __restrict__ W,
        const float* __restrict__ bias, const float* __restrict__ x,
        float* __restrict__ out) {
    __shared__ __bf16 As[128 * 64];
    __shared__ __bf16 Bs[128 * 64];
    int tid = threadIdx.x, wave = tid >> 6, lane = tid & 63;
    int wm = wave >> 1, wn = wave & 1;
    int quad = lane >> 5, lq = lane & 31;
    // XCD-chunked swizzle: nwg=256, 32 per XCD
    int flat = blockIdx.y * gridDim.x + blockIdx.x;
    int nf = (flat & 7) * 32 + (flat >> 3);
    int bm = (nf / 8) * 128, bn = (nf % 8) * 128;

    floatx16 acc[2][2];
#pragma unroll
    for (int i = 0; i < 2; ++i)
#pragma unroll
        for (int j = 0; j < 2; ++j)
#pragma unroll
            for (int r = 0; r < 16; ++r) acc[i][j][r] = 0.f;

    for (int k0 = 0; k0 < EMB_; k0 += 64) {
        __syncthreads();
        stage_tile128(A + (size_t)bm * EMB_ + k0, As, wave, lane);
        stage_tile128(W + (size_t)bn * EMB_ + k0, Bs, wave, lane);
        __syncthreads();
#pragma unroll
        for (int s = 0; s < 4; ++s) {
            int g = 2 * s + quad;
            int r0 = wm * 64 + lq, r1 = r0 + 32;
            int c0 = wn * 64 + lq, c1 = c0 + 32;
            bf16x8 a0 = *(const bf16x8*)&As[r0 * 64 + ((g ^ SWZ(r0)) * 8)];
            bf16x8 a1 = *(const bf16x8*)&As[r1 * 64 + ((g ^ SWZ(r1)) * 8)];
            bf16x8 b0 = *(const bf16x8*)&Bs[c0 * 64 + ((g ^ SWZ(c0)) * 8)];
            bf16x8 b1 = *(const bf16x8*)&Bs[c1 * 64 + ((g ^ SWZ(c1)) * 8)];
            acc[0][0] = MFMA32(a0, b0, acc[0][0]);
            acc[0][1] = MFMA32(a0, b1, acc[0][1]);
            acc[1][0] = MFMA32(a1, b0, acc[1][0]);
            acc[1][1] = MFMA32(a1, b1, acc[1][1]);
        }
    }

#pragma unroll
    for (int mb = 0; mb < 2; ++mb) {
#pragma unroll
        for (int nb = 0; nb < 2; ++nb) {
            int col = bn + wn * 64 + nb * 32 + lq;
            float bv_ = bias[col];
#pragma unroll
            for (int r = 0; r < 16; ++r) {
                size_t row = bm + wm * 64 + mb * 32 + (r & 3) + 8 * (r >> 2) + 4 * quad;
                out[row * EMB_ + col] = acc[mb][nb][r] + bv_ + x[row * EMB_ + col];
            }
        }
    }
}

// ---------------------------------------------------------------------------
// LDS-staged, double-buffered MFMA flash attention — 32 queries per wave,
// 8 waves per block (512 thr, 256 queries/block), LDS 36 KiB/block.
// Round-11 (on the round-10 winner):
//  (a) __launch_bounds__(512, 1): truthful — grid is 256 blocks = 1/CU,
//      8 waves/CU = 2 waves/SIMD (problem-size cap at KSPLIT=1). Raises the
//      per-wave VGPR budget to 256, so ILP additions are register-free.
//  (b) PV accumulator parity split: even k-tiles accumulate into oaccA,
//      odd into oaccB (statically indexed via branch + array reference —
//      rule #20), summed at the end. The 128-deep cross-iteration serial
//      MFMA chain (invisible to the scheduler; t-loop not unrolled) becomes
//      two 64-deep chains -> doubles independent MFMA streams per wave,
//      which is the only latency-hiding available at 2 waves/SIMD.
//  (c) epilogue ds_writes packed 4-wide (dp runs are 4-contiguous):
//      8 ds_write_b64 instead of 32 ds_write_u16 (98K bank-conflict cut).
// Main loop / staging / softmax otherwise identical to round 10.
// Spill tripwire: FETCH must stay ~12.3 MB; VGPR expected ~100-115.
// ---------------------------------------------------------------------------
__global__ __launch_bounds__(512, 1) void attn_mfma(
        const __bf16* __restrict__ Q,   // [4096][1024], pre-scaled
        const __bf16* __restrict__ K,   // [4096][1024]
        const __bf16* __restrict__ Vt,  // [bh][64][2048]
        __bf16* __restrict__ Ob) {      // [4096][1024] final
    __shared__ __bf16 smem[18432];      // 36 KiB: staging (32K) / T[256][72]
    __bf16* KsB = smem;                 // [2][64*64]
    __bf16* VsB = smem + 8192;          // [2][64*64]
    __bf16* Tsm = smem;                 // [256][72]

    int tid = threadIdx.x, wave = tid >> 6, lane = tid & 63;
    int quad = lane >> 5, lq = lane & 31;
    int bh = blockIdx.x;
    int b = bh >> 4, h = bh & 15;
    int q0 = blockIdx.y * 256 + wave * 32;
    const size_t tok0 = (size_t)b * L_;

    const __bf16* Kb = K + tok0 * EMB_ + h * HD_;
    const __bf16* Vb = Vt + (size_t)bh * HD_ * L_;

    // Q fragments: B-operand, 4 k-steps over d=64
    bf16x8 qf[4];
    {
        const __bf16* qp = Q + (tok0 + q0 + lq) * EMB_ + h * HD_ + quad * 8;
#pragma unroll
        for (int s = 0; s < 4; ++s) qf[s] = *(const bf16x8*)(qp + s * 16);
    }

    floatx16 oaccA[2], oaccB[2];   // [db]; parity-split accumulators
#pragma unroll
    for (int j = 0; j < 2; ++j)
#pragma unroll
        for (int r = 0; r < 16; ++r) { oaccA[j][r] = 0.f; oaccB[j][r] = 0.f; }
    float lacc = 0.f;

    int srow = lane >> 3, gch0 = lane & 7;

    // each of the 8 waves stages one 8-row segment of K and of V^T
    auto stage = [&](int buf, int kt) {
        int row = wave * 8 + srow;
        int g = gch0 ^ SWZ(row);
        __builtin_amdgcn_global_load_lds(
            (GV*)(Kb + (size_t)(kt + row) * EMB_ + g * 8),
            (LV*)(KsB + buf * 4096 + wave * 512 + lane * 8), 16, 0, 0);
        __builtin_amdgcn_global_load_lds(
            (GV*)(Vb + (size_t)row * L_ + kt + g * 8),
            (LV*)(VsB + buf * 4096 + wave * 512 + lane * 8), 16, 0, 0);
    };

    auto compute = [&](int buf, floatx16 (&oacc)[2]) {
#pragma unroll
        for (int nb = 0; nb < 2; ++nb) {
            // K fragments (A-operand) for this 32-key block
            int krow = nb * 32 + lq;
            bf16x8 kf[4];
#pragma unroll
            for (int s = 0; s < 4; ++s)
                kf[s] = *(const bf16x8*)(KsB + buf * 4096 + krow * 64 + (((2 * s + quad) ^ SWZ(krow)) * 8));

            floatx16 sacc;
#pragma unroll
            for (int r = 0; r < 16; ++r) sacc[r] = 0.f;
            __builtin_amdgcn_s_setprio(1);
#pragma unroll
            for (int s = 0; s < 4; ++s) sacc = MFMA32(kf[s], qf[s], sacc);
            __builtin_amdgcn_s_setprio(0);

            int P[8];
            float lsum = 0.f;
#pragma unroll
            for (int t = 0; t < 8; ++t) {
                float pa = EXP2(sacc[2 * t]);
                float pb = EXP2(sacc[2 * t + 1]);
                lsum += pa + pb;
                P[t] = pkbf(pa, pb);
            }
            lacc += lsum;
            union { int i[4]; bf16x8 v; } bf0, bf1;
#if __has_builtin(__builtin_amdgcn_permlane32_swap)
            // one swap yields BOTH combined words:
            //  ret[0] = {P_lo[0:31], P_hi[0:31]}  (own low-half word)
            //  ret[1] = {P_lo[32:63], P_hi[32:63]} (other-half word)
            {
                uintx2 r;
                r = __builtin_amdgcn_permlane32_swap((unsigned)P[0], (unsigned)P[2], false, false);
                bf0.i[0] = (int)r[0]; bf0.i[2] = (int)r[1];
                r = __builtin_amdgcn_permlane32_swap((unsigned)P[1], (unsigned)P[3], false, false);
                bf0.i[1] = (int)r[0]; bf0.i[3] = (int)r[1];
                r = __builtin_amdgcn_permlane32_swap((unsigned)P[4], (unsigned)P[6], false, false);
                bf1.i[0] = (int)r[0]; bf1.i[2] = (int)r[1];
                r = __builtin_amdgcn_permlane32_swap((unsigned)P[5], (unsigned)P[7], false, false);
                bf1.i[1] = (int)r[0]; bf1.i[3] = (int)r[1];
            }
#else
            int X[8];
#pragma unroll
            for (int t = 0; t < 8; ++t) X[t] = __shfl_xor(P[t], 32, 64);
            bf0.i[0] = quad ? X[2] : P[0];
            bf0.i[1] = quad ? X[3] : P[1];
            bf0.i[2] = quad ? P[2] : X[0];
            bf0.i[3] = quad ? P[3] : X[1];
            bf1.i[0] = quad ? X[6] : P[4];
            bf1.i[1] = quad ? X[7] : P[5];
            bf1.i[2] = quad ? P[6] : X[4];
            bf1.i[3] = quad ? P[7] : X[5];
#endif

            // V^T fragments for the two 16-key PV steps of this block
            __builtin_amdgcn_s_setprio(1);
#pragma unroll
            for (int half = 0; half < 2; ++half) {
                int t = 2 * nb + half;
#pragma unroll
                for (int db = 0; db < 2; ++db) {
                    int drow = db * 32 + lq;
                    bf16x8 vf = *(const bf16x8*)(VsB + buf * 4096 + drow * 64 + (((2 * t + quad) ^ SWZ(drow)) * 8));
                    oacc[db] = MFMA32(vf, half ? bf1.v : bf0.v, oacc[db]);
                }
            }
            __builtin_amdgcn_s_setprio(0);
        }
    };

    const int NT = L_ / 64;              // 32 tiles of 64 keys — full row

    stage(0, 0);
    for (int t = 0; t < NT; ++t) {
        __syncthreads();                  // buf[t&1] staged (vmcnt drained)
        if (t + 1 < NT) stage((t + 1) & 1, (t + 1) * 64);
        if (t & 1) compute(1, oaccB);     // parity-split: two independent
        else       compute(0, oaccA);     // MFMA accumulation chains
    }

#pragma unroll
    for (int db = 0; db < 2; ++db)
#pragma unroll
        for (int r = 0; r < 16; ++r) oaccA[db][r] += oaccB[db][r];

    // local softmax denominator: combine quad halves — no partials needed
    float l = lacc + __shfl_xor(lacc, 32, 64);
    float rl = 1.0f / l;

    // normalize + transpose in LDS, write token-major Ob
    __syncthreads();                      // all waves done with staging LDS
    int qloc = wave * 32 + lq;
#pragma unroll
    for (int db = 0; db < 2; ++db)
#pragma unroll
        for (int rg = 0; rg < 4; ++rg) {  // dp runs of 4: packed b64 writes
            int dpb = db * 32 + 8 * rg + 4 * quad;
            bf16x4 t4;
#pragma unroll
            for (int a = 0; a < 4; ++a)
                t4[a] = (__bf16)(oaccA[db][4 * rg + a] * rl);
            *(bf16x4*)&Tsm[qloc * 72 + dpb] = t4;
        }
    __syncthreads();
    int qblk = blockIdx.y * 256;
#pragma unroll
    for (int cc = 0; cc < 4; ++cc) {
        int tl = cc * 64 + (tid >> 3), dc = (tid & 7) * 8;
        bf16x8 v = *(const bf16x8*)&Tsm[tl * 72 + dc];
        *(bf16x8*)(Ob + ((size_t)b * L_ + qblk + tl) * EMB_ + h * HD_ + dc) = v;
    }
}

// ---------------------------------------------------------------------------
extern "C" void kernel_launch(void* const* d_in, const int* in_sizes, int n_in,
                              void* d_out, int out_size, void* d_ws, size_t ws_size,
                              hipStream_t stream) {
    const float* x     = (const float*)d_in[0];
    const float* gamma = (const float*)d_in[1];
    const float* beta  = (const float*)d_in[2];
    const float* Wq    = (const float*)d_in[3];
    const float* bq    = (const float*)d_in[4];
    const float* Wk    = (const float*)d_in[5];
    const float* bk    = (const float*)d_in[6];
    const float* Wv    = (const float*)d_in[7];
    const float* bv    = (const float*)d_in[8];
    const float* Wo    = (const float*)d_in[9];
    const float* bo    = (const float*)d_in[10];
    float* out = (float*)d_out;

    const size_t SLAB = (size_t)M_ * EMB_;        // activation elements
    const size_t WSLAB = (size_t)EMB_ * EMB_;     // weight elements
    char* ws = (char*)d_ws;
    __bf16* hb    = (__bf16*)ws;                      ws += SLAB * 2;
    __bf16* Qb    = (__bf16*)ws;                      ws += SLAB * 2;
    __bf16* Kb    = (__bf16*)ws;                      ws += SLAB * 2;
    __bf16* Vtb   = (__bf16*)ws;                      ws += SLAB * 2;
    __bf16* Wqkvb = (__bf16*)ws;                      ws += 3 * WSLAB * 2;
    __bf16* Wob   = (__bf16*)ws;                      ws += WSLAB * 2;
    __bf16* Ob    = hb;   // hb dead after gemm_qkv; reuse for attention output

    prep_kernel<<<M_ + 1024, 256, 0, stream>>>(
        x, gamma, beta, hb,
        Wq, Wk, Wv, Wo, Wqkvb, Wqkvb + WSLAB, Wqkvb + 2 * WSLAB, Wob);
    gemm_qkv_mfma<<<dim3(3 * EMB_ / 128, M_ / 128), 256, 0, stream>>>(
        hb, Wqkvb, bq, bk, bv, Qb, Kb, Vtb);
    attn_mfma<<<dim3(B_ * H_, L_ / 256), 512, 0, stream>>>(
        Qb, Kb, Vtb, Ob);
    gemm_out_mfma<<<dim3(EMB_ / 128, M_ / 128), 256, 0, stream>>>(
        Ob, Wob, bo, x, out);
}

// Round 12
// 188.473 us; speedup vs baseline: 1.0566x; 1.0566x over previous
//
#include <hip/hip_runtime.h>
#include <math.h>

#define B_   2
#define L_   2048
#define EMB_ 1024
#define H_   16
#define HD_  64
#define M_   (B_ * L_)   // 4096 tokens
#define LOG2E 1.44269504088896f

typedef __bf16 bf16x8 __attribute__((ext_vector_type(8)));
typedef __bf16 bf16x4 __attribute__((ext_vector_type(4)));
typedef __bf16 bf16x2 __attribute__((ext_vector_type(2)));
typedef float floatx16 __attribute__((ext_vector_type(16)));
typedef unsigned int uintx2 __attribute__((ext_vector_type(2)));

typedef __attribute__((address_space(1))) const void GV;
typedef __attribute__((address_space(3))) void LV;

#define MFMA32(a, b, c) __builtin_amdgcn_mfma_f32_32x32x16_bf16((a), (b), (c), 0, 0, 0)

#if __has_builtin(__builtin_amdgcn_exp2f)
#define EXP2(x) __builtin_amdgcn_exp2f(x)
#else
#define EXP2(x) exp2f(x)
#endif

// LDS chunk swizzle: lanes lq, lq+8, lq+16, lq+24 (same (row&7)) get distinct
// chunk slots via the (row>>3)&3 term.
#define SWZ(row) ((((row) & 7) ^ (((row) >> 3) & 3)))

// pack two floats into a bf16 pair (b32)
__device__ __forceinline__ int pkbf(float a, float b) {
#if __has_builtin(__builtin_amdgcn_cvt_pk_bf16_f32)
    union { bf16x2 v; int i; } u;
    u.v = __builtin_amdgcn_cvt_pk_bf16_f32(a, b);
    return u.i;
#else
    union { __bf16 h[2]; int i; } u;
    u.h[0] = (__bf16)a; u.h[1] = (__bf16)b;
    return u.i;
#endif
}

// ---------------------------------------------------------------------------
// Fused prep: blocks [0, M_) do LayerNorm -> bf16 (one block per token row);
// blocks [M_, M_+1024) convert the 4 weight slabs fp32 -> bf16.
// ---------------------------------------------------------------------------
__global__ __launch_bounds__(256) void prep_kernel(
        const float* __restrict__ x, const float* __restrict__ gamma,
        const float* __restrict__ beta, __bf16* __restrict__ h,
        const float* __restrict__ s0, const float* __restrict__ s1,
        const float* __restrict__ s2, const float* __restrict__ s3,
        __bf16* __restrict__ d0, __bf16* __restrict__ d1,
        __bf16* __restrict__ d2, __bf16* __restrict__ d3) {
    int bid = blockIdx.x;
    int tid = threadIdx.x;
    if (bid >= M_) {
        int wb = bid - M_;                 // 0..1023
        int z = wb >> 8;                   // slab
        const float* s = (z == 0) ? s0 : (z == 1) ? s1 : (z == 2) ? s2 : s3;
        __bf16* d = (z == 0) ? d0 : (z == 1) ? d1 : (z == 2) ? d2 : d3;
        size_t base = (size_t)((wb & 255) * 256 + tid) * 16;
#pragma unroll
        for (int j = 0; j < 4; ++j) {
            float4 f = *(const float4*)(s + base + j * 4);
            bf16x4 t;
            t[0] = (__bf16)f.x; t[1] = (__bf16)f.y; t[2] = (__bf16)f.z; t[3] = (__bf16)f.w;
            *(bf16x4*)(d + base + j * 4) = t;
        }
        return;
    }
    int row = bid;
    const float* xr = x + (size_t)row * EMB_;
    float4 v = *(const float4*)(xr + tid * 4);
    float s  = v.x + v.y + v.z + v.w;
    float ss = v.x * v.x + v.y * v.y + v.z * v.z + v.w * v.w;
    for (int off = 32; off; off >>= 1) {
        s  += __shfl_down(s, off, 64);
        ss += __shfl_down(ss, off, 64);
    }
    __shared__ float s1_[4], s2_[4];
    int wid = tid >> 6;
    if ((tid & 63) == 0) { s1_[wid] = s; s2_[wid] = ss; }
    __syncthreads();
    if (tid == 0) {
        float a = s1_[0] + s1_[1] + s1_[2] + s1_[3];
        float b = s2_[0] + s2_[1] + s2_[2] + s2_[3];
        float mu = a / EMB_;
        float var = b / EMB_ - mu * mu;
        s1_[0] = mu;
        s2_[0] = rsqrtf(var + 1e-5f);
    }
    __syncthreads();
    float mu = s1_[0], rstd = s2_[0];
    float4 g4 = *(const float4*)(gamma + tid * 4);
    float4 b4 = *(const float4*)(beta + tid * 4);
    bf16x4 o;
    o[0] = (__bf16)((v.x - mu) * rstd * g4.x + b4.x);
    o[1] = (__bf16)((v.y - mu) * rstd * g4.y + b4.y);
    o[2] = (__bf16)((v.z - mu) * rstd * g4.z + b4.z);
    o[3] = (__bf16)((v.w - mu) * rstd * g4.w + b4.w);
    *(bf16x4*)(h + (size_t)row * EMB_ + tid * 4) = o;
}

// ---------------------------------------------------------------------------
// GEMM staging: 128 rows x 64 cols bf16 tile, SWZ-swizzled 16B chunks.
// ---------------------------------------------------------------------------
__device__ __forceinline__ void stage_tile128(const __bf16* gbase, __bf16* lds,
                                              int wave, int lane) {
    int srow = lane >> 3;
    int gch0 = lane & 7;
#pragma unroll
    for (int s = 0; s < 4; ++s) {
        int seg = wave * 4 + s;
        int row = seg * 8 + srow;
        int g = gch0 ^ SWZ(row);
        __builtin_amdgcn_global_load_lds(
            (GV*)(gbase + (size_t)row * EMB_ + g * 8),
            (LV*)(lds + seg * 512 + lane * 8), 16, 0, 0);
    }
}

// ---------------------------------------------------------------------------
// Fused QKV projection GEMM: C = h @ Wqkv^T + bias, 128x128 tile, BK=64.
// Wqkv = [3072][1024] (Wq; Wk; Wv). Column block z = col>>10 selects output:
// z=0 -> Q (scaled by 0.125*log2e), z=1 -> K, z=2 -> V^T ([b][h][d][l]).
// XCD-chunked blockIdx swizzle (T1): grid 768, 96 tiles per XCD.
// ---------------------------------------------------------------------------
__global__ __launch_bounds__(256) void gemm_qkv_mfma(
        const __bf16* __restrict__ A, const __bf16* __restrict__ W,
        const float* __restrict__ bq, const float* __restrict__ bk,
        const float* __restrict__ bv,
        __bf16* __restrict__ Qo, __bf16* __restrict__ Ko,
        __bf16* __restrict__ Vto) {
    __shared__ __bf16 As[128 * 64];
    __shared__ __bf16 Bs[128 * 64];
    int tid = threadIdx.x, wave = tid >> 6, lane = tid & 63;
    int wm = wave >> 1, wn = wave & 1;
    int quad = lane >> 5, lq = lane & 31;
    // XCD-chunked swizzle: nwg=768, 96 per XCD
    int flat = blockIdx.y * gridDim.x + blockIdx.x;
    int nf = (flat & 7) * 96 + (flat >> 3);
    int bm = (nf / 24) * 128, bn = (nf % 24) * 128;

    floatx16 acc[2][2];
#pragma unroll
    for (int i = 0; i < 2; ++i)
#pragma unroll
        for (int j = 0; j < 2; ++j)
#pragma unroll
            for (int r = 0; r < 16; ++r) acc[i][j][r] = 0.f;

    for (int k0 = 0; k0 < EMB_; k0 += 64) {
        __syncthreads();
        stage_tile128(A + (size_t)bm * EMB_ + k0, As, wave, lane);
        stage_tile128(W + (size_t)bn * EMB_ + k0, Bs, wave, lane);
        __syncthreads();
#pragma unroll
        for (int s = 0; s < 4; ++s) {
            int g = 2 * s + quad;
            int r0 = wm * 64 + lq, r1 = r0 + 32;
            int c0 = wn * 64 + lq, c1 = c0 + 32;
            bf16x8 a0 = *(const bf16x8*)&As[r0 * 64 + ((g ^ SWZ(r0)) * 8)];
            bf16x8 a1 = *(const bf16x8*)&As[r1 * 64 + ((g ^ SWZ(r1)) * 8)];
            bf16x8 b0 = *(const bf16x8*)&Bs[c0 * 64 + ((g ^ SWZ(c0)) * 8)];
            bf16x8 b1 = *(const bf16x8*)&Bs[c1 * 64 + ((g ^ SWZ(c1)) * 8)];
            acc[0][0] = MFMA32(a0, b0, acc[0][0]);
            acc[0][1] = MFMA32(a0, b1, acc[0][1]);
            acc[1][0] = MFMA32(a1, b0, acc[1][0]);
            acc[1][1] = MFMA32(a1, b1, acc[1][1]);
        }
    }

#pragma unroll
    for (int mb = 0; mb < 2; ++mb) {
#pragma unroll
        for (int nb = 0; nb < 2; ++nb) {
            int col = bn + wn * 64 + nb * 32 + lq;
            int z = col >> 10;
            int cc = col & 1023;
            float bv_ = (z == 0) ? bq[cc] : (z == 1) ? bk[cc] : bv[cc];
            if (z < 2) {
                __bf16* dst = (z == 0) ? Qo : Ko;
                float qs = (z == 0) ? 0.125f * LOG2E : 1.0f;
#pragma unroll
                for (int r = 0; r < 16; ++r) {
                    int row = bm + wm * 64 + mb * 32 + (r & 3) + 8 * (r >> 2) + 4 * quad;
                    dst[(size_t)row * EMB_ + cc] = (__bf16)((acc[mb][nb][r] + bv_) * qs);
                }
            } else {
                int hh = cc >> 6, d = cc & 63;
#pragma unroll
                for (int rb = 0; rb < 4; ++rb) {
                    int row = bm + wm * 64 + mb * 32 + 8 * rb + 4 * quad;
                    int b = row >> 11, l = row & (L_ - 1);
                    bf16x4 t;
#pragma unroll
                    for (int a = 0; a < 4; ++a) t[a] = (__bf16)(acc[mb][nb][4 * rb + a] + bv_);
                    *(bf16x4*)(Vto + ((size_t)(b * H_ + hh) * HD_ + d) * L_ + l) = t;
                }
            }
        }
    }
}

// ---------------------------------------------------------------------------
// Output projection GEMM: out = O @ Wo^T + bo + x (fp32 out). 128x128 tile.
// XCD-chunked swizzle (grid 256, 32 per XCD).
// ---------------------------------------------------------------------------
__global__ __launch_bounds__(256) void gemm_out_mfma(
        const __bf16* __restrict__ A, const __bf16* __restrict__ W,
        const float* __restrict__ bias, const float* __restrict__ x,
        float* __restrict__ out) {
    __shared__ __bf16 As[128 * 64];
    __shared__ __bf16 Bs[128 * 64];
    int tid = threadIdx.x, wave = tid >> 6, lane = tid & 63;
    int wm = wave >> 1, wn = wave & 1;
    int quad = lane >> 5, lq = lane & 31;
    // XCD-chunked swizzle: nwg=256, 32 per XCD
    int flat = blockIdx.y * gridDim.x + blockIdx.x;
    int nf = (flat & 7) * 32 + (flat >> 3);
    int bm = (nf / 8) * 128, bn = (nf % 8) * 128;

    floatx16 acc[2][2];
#pragma unroll
    for (int i = 0; i < 2; ++i)
#pragma unroll
        for (int j = 0; j < 2; ++j)
#pragma unroll
            for (int r = 0; r < 16; ++r) acc[i][j][r] = 0.f;

    for (int k0 = 0; k0 < EMB_; k0 += 64) {
        __syncthreads();
        stage_tile128(A + (size_t)bm * EMB_ + k0, As, wave, lane);
        stage_tile128(W + (size_t)bn * EMB_ + k0, Bs, wave, lane);
        __syncthreads();
#pragma unroll
        for (int s = 0; s < 4; ++s) {
            int g = 2 * s + quad;
            int r0 = wm * 64 + lq, r1 = r0 + 32;
            int c0 = wn * 64 + lq, c1 = c0 + 32;
            bf16x8 a0 = *(const bf16x8*)&As[r0 * 64 + ((g ^ SWZ(r0)) * 8)];
            bf16x8 a1 = *(const bf16x8*)&As[r1 * 64 + ((g ^ SWZ(r1)) * 8)];
            bf16x8 b0 = *(const bf16x8*)&Bs[c0 * 64 + ((g ^ SWZ(c0)) * 8)];
            bf16x8 b1 = *(const bf16x8*)&Bs[c1 * 64 + ((g ^ SWZ(c1)) * 8)];
            acc[0][0] = MFMA32(a0, b0, acc[0][0]);
            acc[0][1] = MFMA32(a0, b1, acc[0][1]);
            acc[1][0] = MFMA32(a1, b0, acc[1][0]);
            acc[1][1] = MFMA32(a1, b1, acc[1][1]);
        }
    }

#pragma unroll
    for (int mb = 0; mb < 2; ++mb) {
#pragma unroll
        for (int nb = 0; nb < 2; ++nb) {
            int col = bn + wn * 64 + nb * 32 + lq;
            float bv_ = bias[col];
#pragma unroll
            for (int r = 0; r < 16; ++r) {
                size_t row = bm + wm * 64 + mb * 32 + (r & 3) + 8 * (r >> 2) + 4 * quad;
                out[row * EMB_ + col] = acc[mb][nb][r] + bv_ + x[row * EMB_ + col];
            }
        }
    }
}

// ---------------------------------------------------------------------------
// LDS-staged, double-buffered MFMA flash attention — 32 queries per wave,
// 8 waves per block (512 thr, 256 queries/block), LDS 36 KiB/block.
// Round-12: byte-identical revert to the round-10 winner (49.5 us attn,
// 188.9 us total — session best). Round-11's parity-split accumulators
// regressed (+4 us): the cross-tile oacc chain was already broken by the
// softmax VALU between PV clusters, so the split added register pressure
// (VGPR 72->96) without new ILP. Three attn levers (explicit pipelining r6,
// cross-block combine r9, accumulator split r11) have each failed with
// counter evidence — this structure is the verified local optimum:
// VALU-issue-bound at the problem-size-capped 8 waves/CU.
// NO split-K: one dispatch, grid (32 bh, 8 qblk) = 256 blocks; each block
// walks all 2048 keys (NT=32), normalizes locally, writes token-major Ob
// via the LDS-transpose epilogue.
// smem union: staging 2x(2x64x64) = 32 KiB; transpose T[256][72] = 36 KiB.
// ---------------------------------------------------------------------------
__global__ __launch_bounds__(512, 2) void attn_mfma(
        const __bf16* __restrict__ Q,   // [4096][1024], pre-scaled
        const __bf16* __restrict__ K,   // [4096][1024]
        const __bf16* __restrict__ Vt,  // [bh][64][2048]
        __bf16* __restrict__ Ob) {      // [4096][1024] final
    __shared__ __bf16 smem[18432];      // 36 KiB: staging (32K) / T[256][72]
    __bf16* KsB = smem;                 // [2][64*64]
    __bf16* VsB = smem + 8192;          // [2][64*64]
    __bf16* Tsm = smem;                 // [256][72]

    int tid = threadIdx.x, wave = tid >> 6, lane = tid & 63;
    int quad = lane >> 5, lq = lane & 31;
    int bh = blockIdx.x;
    int b = bh >> 4, h = bh & 15;
    int q0 = blockIdx.y * 256 + wave * 32;
    const size_t tok0 = (size_t)b * L_;

    const __bf16* Kb = K + tok0 * EMB_ + h * HD_;
    const __bf16* Vb = Vt + (size_t)bh * HD_ * L_;

    // Q fragments: B-operand, 4 k-steps over d=64
    bf16x8 qf[4];
    {
        const __bf16* qp = Q + (tok0 + q0 + lq) * EMB_ + h * HD_ + quad * 8;
#pragma unroll
        for (int s = 0; s < 4; ++s) qf[s] = *(const bf16x8*)(qp + s * 16);
    }

    floatx16 oacc[2];   // [db]
#pragma unroll
    for (int j = 0; j < 2; ++j)
#pragma unroll
        for (int r = 0; r < 16; ++r) oacc[j][r] = 0.f;
    float lacc = 0.f;

    int srow = lane >> 3, gch0 = lane & 7;

    // each of the 8 waves stages one 8-row segment of K and of V^T
    auto stage = [&](int buf, int kt) {
        int row = wave * 8 + srow;
        int g = gch0 ^ SWZ(row);
        __builtin_amdgcn_global_load_lds(
            (GV*)(Kb + (size_t)(kt + row) * EMB_ + g * 8),
            (LV*)(KsB + buf * 4096 + wave * 512 + lane * 8), 16, 0, 0);
        __builtin_amdgcn_global_load_lds(
            (GV*)(Vb + (size_t)row * L_ + kt + g * 8),
            (LV*)(VsB + buf * 4096 + wave * 512 + lane * 8), 16, 0, 0);
    };

    auto compute = [&](int buf) {
#pragma unroll
        for (int nb = 0; nb < 2; ++nb) {
            // K fragments (A-operand) for this 32-key block
            int krow = nb * 32 + lq;
            bf16x8 kf[4];
#pragma unroll
            for (int s = 0; s < 4; ++s)
                kf[s] = *(const bf16x8*)(KsB + buf * 4096 + krow * 64 + (((2 * s + quad) ^ SWZ(krow)) * 8));

            floatx16 sacc;
#pragma unroll
            for (int r = 0; r < 16; ++r) sacc[r] = 0.f;
            __builtin_amdgcn_s_setprio(1);
#pragma unroll
            for (int s = 0; s < 4; ++s) sacc = MFMA32(kf[s], qf[s], sacc);
            __builtin_amdgcn_s_setprio(0);

            int P[8];
            float lsum = 0.f;
#pragma unroll
            for (int t = 0; t < 8; ++t) {
                float pa = EXP2(sacc[2 * t]);
                float pb = EXP2(sacc[2 * t + 1]);
                lsum += pa + pb;
                P[t] = pkbf(pa, pb);
            }
            lacc += lsum;
            union { int i[4]; bf16x8 v; } bf0, bf1;
#if __has_builtin(__builtin_amdgcn_permlane32_swap)
            // one swap yields BOTH combined words:
            //  ret[0] = {P_lo[0:31], P_hi[0:31]}  (own low-half word)
            //  ret[1] = {P_lo[32:63], P_hi[32:63]} (other-half word)
            {
                uintx2 r;
                r = __builtin_amdgcn_permlane32_swap((unsigned)P[0], (unsigned)P[2], false, false);
                bf0.i[0] = (int)r[0]; bf0.i[2] = (int)r[1];
                r = __builtin_amdgcn_permlane32_swap((unsigned)P[1], (unsigned)P[3], false, false);
                bf0.i[1] = (int)r[0]; bf0.i[3] = (int)r[1];
                r = __builtin_amdgcn_permlane32_swap((unsigned)P[4], (unsigned)P[6], false, false);
                bf1.i[0] = (int)r[0]; bf1.i[2] = (int)r[1];
                r = __builtin_amdgcn_permlane32_swap((unsigned)P[5], (unsigned)P[7], false, false);
                bf1.i[1] = (int)r[0]; bf1.i[3] = (int)r[1];
            }
#else
            int X[8];
#pragma unroll
            for (int t = 0; t < 8; ++t) X[t] = __shfl_xor(P[t], 32, 64);
            bf0.i[0] = quad ? X[2] : P[0];
            bf0.i[1] = quad ? X[3] : P[1];
            bf0.i[2] = quad ? P[2] : X[0];
            bf0.i[3] = quad ? P[3] : X[1];
            bf1.i[0] = quad ? X[6] : P[4];
            bf1.i[1] = quad ? X[7] : P[5];
            bf1.i[2] = quad ? P[6] : X[4];
            bf1.i[3] = quad ? P[7] : X[5];
#endif

            // V^T fragments for the two 16-key PV steps of this block
            __builtin_amdgcn_s_setprio(1);
#pragma unroll
            for (int half = 0; half < 2; ++half) {
                int t = 2 * nb + half;
#pragma unroll
                for (int db = 0; db < 2; ++db) {
                    int drow = db * 32 + lq;
                    bf16x8 vf = *(const bf16x8*)(VsB + buf * 4096 + drow * 64 + (((2 * t + quad) ^ SWZ(drow)) * 8));
                    oacc[db] = MFMA32(vf, half ? bf1.v : bf0.v, oacc[db]);
                }
            }
            __builtin_amdgcn_s_setprio(0);
        }
    };

    const int NT = L_ / 64;              // 32 tiles of 64 keys — full row

    stage(0, 0);
    for (int t = 0; t < NT; ++t) {
        __syncthreads();                  // buf[t&1] staged (vmcnt drained)
        if (t + 1 < NT) stage((t + 1) & 1, (t + 1) * 64);
        compute(t & 1);
    }

    // local softmax denominator: combine quad halves — no partials needed
    float l = lacc + __shfl_xor(lacc, 32, 64);
    float rl = 1.0f / l;

    // normalize + transpose in LDS, write token-major Ob (round-8 epilogue)
    __syncthreads();                      // all waves done with staging LDS
    int qloc = wave * 32 + lq;
#pragma unroll
    for (int db = 0; db < 2; ++db)
#pragma unroll
        for (int r = 0; r < 16; ++r) {
            int dp = db * 32 + (r & 3) + 8 * (r >> 2) + 4 * quad;
            Tsm[qloc * 72 + dp] = (__bf16)(oacc[db][r] * rl);
        }
    __syncthreads();
    int qblk = blockIdx.y * 256;
#pragma unroll
    for (int cc = 0; cc < 4; ++cc) {
        int tl = cc * 64 + (tid >> 3), dc = (tid & 7) * 8;
        bf16x8 v = *(const bf16x8*)&Tsm[tl * 72 + dc];
        *(bf16x8*)(Ob + ((size_t)b * L_ + qblk + tl) * EMB_ + h * HD_ + dc) = v;
    }
}

// ---------------------------------------------------------------------------
extern "C" void kernel_launch(void* const* d_in, const int* in_sizes, int n_in,
                              void* d_out, int out_size, void* d_ws, size_t ws_size,
                              hipStream_t stream) {
    const float* x     = (const float*)d_in[0];
    const float* gamma = (const float*)d_in[1];
    const float* beta  = (const float*)d_in[2];
    const float* Wq    = (const float*)d_in[3];
    const float* bq    = (const float*)d_in[4];
    const float* Wk    = (const float*)d_in[5];
    const float* bk    = (const float*)d_in[6];
    const float* Wv    = (const float*)d_in[7];
    const float* bv    = (const float*)d_in[8];
    const float* Wo    = (const float*)d_in[9];
    const float* bo    = (const float*)d_in[10];
    float* out = (float*)d_out;

    const size_t SLAB = (size_t)M_ * EMB_;        // activation elements
    const size_t WSLAB = (size_t)EMB_ * EMB_;     // weight elements
    char* ws = (char*)d_ws;
    __bf16* hb    = (__bf16*)ws;                      ws += SLAB * 2;
    __bf16* Qb    = (__bf16*)ws;                      ws += SLAB * 2;
    __bf16* Kb    = (__bf16*)ws;                      ws += SLAB * 2;
    __bf16* Vtb   = (__bf16*)ws;                      ws += SLAB * 2;
    __bf16* Wqkvb = (__bf16*)ws;                      ws += 3 * WSLAB * 2;
    __bf16* Wob   = (__bf16*)ws;                      ws += WSLAB * 2;
    __bf16* Ob    = hb;   // hb dead after gemm_qkv; reuse for attention output

    prep_kernel<<<M_ + 1024, 256, 0, stream>>>(
        x, gamma, beta, hb,
        Wq, Wk, Wv, Wo, Wqkvb, Wqkvb + WSLAB, Wqkvb + 2 * WSLAB, Wob);
    gemm_qkv_mfma<<<dim3(3 * EMB_ / 128, M_ / 128), 256, 0, stream>>>(
        hb, Wqkvb, bq, bk, bv, Qb, Kb, Vtb);
    attn_mfma<<<dim3(B_ * H_, L_ / 256), 512, 0, stream>>>(
        Qb, Kb, Vtb, Ob);
    gemm_out_mfma<<<dim3(EMB_ / 128, M_ / 128), 256, 0, stream>>>(
        Ob, Wob, bo, x, out);
}